// Round 16
// baseline (112.223 us; speedup 1.0000x reference)
//
#include <hip/hip_runtime.h>

#define NUM_EMB 1024
#define DIM     256
#define NPIX    32768      // 32 * 32 * 32
#define NELEM   8388608    // 32 * 256 * 32 * 32

typedef unsigned short u16;
typedef unsigned int   u32;
typedef __attribute__((ext_vector_type(8))) _Float16 f16x8;
typedef __attribute__((ext_vector_type(4))) float f32x4;

__device__ __forceinline__ u16 f32_f16(float f) {
    _Float16 h = (_Float16)f;                  // v_cvt_f16_f32, RN-even
    return __builtin_bit_cast(u16, h);
}
__device__ __forceinline__ float f16_f32(u16 b) {
    return (float)__builtin_bit_cast(_Float16, b);
}

// ===========================================================================
// MFMA path — f16 2-term split, SINGLE-accumulator 3-pair formulation:
//   x = 4*(Xa + 2^-10*Xb + eps), e = 2^-11*(Ea + 2^-10*Eb + eps)
//   pre-scaled B operands: Ea2 = f16(Ea*2^-10), Eb2 = f16(Eb*2^-10)
//   acc += Xa*Ea + Xb*Ea2 + Xa*Eb2  =>  2*x*e = 2^-8 * acc
// ===========================================================================

// ---------------------------------------------------------------------------
// prep_x: split x into Xa,Xb f16 arrays, frag-major [kc8][kb4][px][8k];
// |x|^2 per pixel.
// ---------------------------------------------------------------------------
__global__ __launch_bounds__(256) void k_prep_x(const float* __restrict__ x,
        u16* __restrict__ Xa, u16* __restrict__ Xb,
        float* __restrict__ nx_out)
{
    __shared__ float nxp[4][64];
    const int t  = threadIdx.x;
    const int p  = t & 63;
    const int cq = t >> 6;
    const int bi = blockIdx.x;            // 512
    const int b  = bi >> 4;
    const int hw = ((bi & 15) << 6) + p;
    const float* xp = x + (((size_t)(b * 256 + cq * 64)) << 10) + hw;
    float s = 0.f;
    for (int i0 = 0; i0 < 64; i0 += 8) {
        u32 qa[4], qb[4];
#pragma unroll
        for (int j = 0; j < 8; ++j) {
            float v = xp[(size_t)(i0 + j) << 10];
            s = fmaf(v, v, s);
            float va = v * 0.25f;                  // exact
            u16 ha = f32_f16(va);
            float rb = (va - f16_f32(ha)) * 1024.0f;   // exact (Sterbenz + pow2)
            u16 hb = f32_f16(rb);
            if ((j & 1) == 0) { qa[j>>1] = ha; qb[j>>1] = hb; }
            else { qa[j>>1] |= (u32)ha << 16; qb[j>>1] |= (u32)hb << 16; }
        }
        const int c = cq * 64 + i0;
        const size_t chunk = (((size_t)((c >> 5) * 4 + ((c >> 3) & 3))) << 15)
                             + (size_t)bi * 64 + p;
        *(uint4*)(Xa + chunk * 8) = make_uint4(qa[0], qa[1], qa[2], qa[3]);
        *(uint4*)(Xb + chunk * 8) = make_uint4(qb[0], qb[1], qb[2], qb[3]);
    }
    nxp[cq][p] = s;
    __syncthreads();
    if (t < 64)
        nx_out[bi * 64 + t] = ((nxp[0][t] + nxp[1][t]) + nxp[2][t]) + nxp[3][t];
}

// ---------------------------------------------------------------------------
// prep_e: split codebook -> Ea, Ea2=Ea*2^-10, Eb2=Eb*2^-10 (frag-major) + |e|^2
// ---------------------------------------------------------------------------
__global__ __launch_bounds__(256) void k_prep_e(const float* __restrict__ cb,
        u16* __restrict__ Ea, u16* __restrict__ Ea2, u16* __restrict__ Eb2,
        float* __restrict__ ne_out)
{
    const int t = threadIdx.x;
    const int l32 = t & 31;
    const int code = blockIdx.x * 8 + (t >> 5);
    const float* cp = cb + (size_t)code * 256 + l32 * 8;
    u32 qa[4], qa2[4], qb2[4];
    float s = 0.f;
#pragma unroll
    for (int j = 0; j < 8; ++j) {
        float v = cp[j];
        s = fmaf(v, v, s);
        float va = v * 2048.0f;                    // exact
        u16 ha = f32_f16(va);
        float rb = (va - f16_f32(ha)) * 1024.0f;   // exact
        u16 hb = f32_f16(rb);
        u16 ha2 = f32_f16(f16_f32(ha) * 9.765625e-04f);  // Ea*2^-10
        u16 hb2 = f32_f16(f16_f32(hb) * 9.765625e-04f);  // Eb*2^-10
        if ((j & 1) == 0) { qa[j>>1] = ha; qa2[j>>1] = ha2; qb2[j>>1] = hb2; }
        else { qa[j>>1] |= (u32)ha << 16; qa2[j>>1] |= (u32)ha2 << 16; qb2[j>>1] |= (u32)hb2 << 16; }
    }
    const size_t chunk = ((size_t)l32 << 10) + code;
    *(uint4*)(Ea  + chunk * 8) = make_uint4(qa[0],  qa[1],  qa[2],  qa[3]);
    *(uint4*)(Ea2 + chunk * 8) = make_uint4(qa2[0], qa2[1], qa2[2], qa2[3]);
    *(uint4*)(Eb2 + chunk * 8) = make_uint4(qb2[0], qb2[1], qb2[2], qb2[3]);
#pragma unroll
    for (int off = 16; off > 0; off >>= 1) s += __shfl_xor(s, off);
    if (l32 == 0) ne_out[code] = s;
}

// ---------------------------------------------------------------------------
// MFMA distance-argmin. Round-16: BARRIER-FREE free-run (r5 structure) x
// single-acc 3-pair f16 (r15 math):
//   - wave = 64px x 32codes; block = 4 waves (128 codes); grid 4096
//   - NO LDS, NO barriers in the K-loop: per wave per kc, 8 A-frag + 6
//     B-frag global->reg loads (frag-major 256B segments, L2/L1-resident;
//     A duplicates across the block's 4 waves hit L1) + 24 MFMAs.
//   - fully unrolled: compiler hoists kc+1 loads over kc MFMAs (r5 showed
//     45% MfmaUtil in this structure — the best measured in this session);
//     free-running waves stagger instead of barrier-convoying.
//   - acc = 32 AGPR; ~80 VGPR -> launch_bounds(256,4), no spill expected
//     (r11/r13 check: WRITE_SIZE must stay ~2MB).
//   - same per-acc MFMA order as r15 -> bit-identical scores.
// ---------------------------------------------------------------------------
__global__ __launch_bounds__(256, 4) void k_mfma_argmin(
        const u16* __restrict__ XA, const u16* __restrict__ XB,
        const u16* __restrict__ EA, const u16* __restrict__ EA2,
        const u16* __restrict__ EB2,
        const float* __restrict__ nx, const float* __restrict__ ne,
        float* __restrict__ partV, int* __restrict__ partI)
{
    __shared__ float redV[4][64];
    __shared__ int   redI[4][64];

    const int t = threadIdx.x;
    const int l = t & 63;
    const int w = t >> 6;

    // XCD-aware bijective swizzle (grid 4096 % 8 == 0)
    const int bi   = blockIdx.x;
    const int xcd  = bi & 7;
    const int slot = bi >> 3;
    const int cT   = slot & 7;
    const int pT   = ((slot >> 3) << 3) | xcd;     // [0, 512)
    const int px0  = pT << 6;                      // 64-px tile
    const int c0   = cT << 7;                      // 128-code tile
    const int n0   = w << 5;                       // wave owns 32 codes
    const int kbl  = l >> 4;
    const int il   = l & 15;

    f32x4 acc[4][2];
#pragma unroll
    for (int i = 0; i < 4; ++i)
#pragma unroll
        for (int j = 0; j < 2; ++j) acc[i][j] = (f32x4){0.f, 0.f, 0.f, 0.f};

    // per-lane base pointers (elements):
    //  A(T,mi,kc) = Xt + kbl*262144 + (px0+il)*8 + kc*1048576 + mi*128
    //  B(T,ni,kc) = Et + kbl*8192   + (c0+n0+il)*8 + kc*32768 + ni*128
    const size_t aoff = (size_t)kbl * 262144 + (size_t)(px0 + il) * 8;
    const size_t boff = (size_t)kbl * 8192   + (size_t)(c0 + n0 + il) * 8;
    const u16* pXa  = XA  + aoff;
    const u16* pXb  = XB  + aoff;
    const u16* pBa  = EA  + boff;
    const u16* pBa2 = EA2 + boff;
    const u16* pBb2 = EB2 + boff;

#pragma unroll
    for (int kc = 0; kc < 8; ++kc) {
        const size_t ao = (size_t)kc * 1048576;
        const size_t bo = (size_t)kc * 32768;

        f16x8 afa[4], afb[4];
#pragma unroll
        for (int mi = 0; mi < 4; ++mi) {
            afa[mi] = *(const f16x8*)(pXa + ao + mi * 128);
            afb[mi] = *(const f16x8*)(pXb + ao + mi * 128);
        }
        f16x8 bqa[2], bq2a[2], bq2b[2];
#pragma unroll
        for (int ni = 0; ni < 2; ++ni) {
            bqa[ni]  = *(const f16x8*)(pBa  + bo + ni * 128);
            bq2a[ni] = *(const f16x8*)(pBa2 + bo + ni * 128);
            bq2b[ni] = *(const f16x8*)(pBb2 + bo + ni * 128);
        }

        __builtin_amdgcn_s_setprio(1);
#pragma unroll
        for (int mi = 0; mi < 4; ++mi)
#pragma unroll
            for (int ni = 0; ni < 2; ++ni) {
                acc[mi][ni] = __builtin_amdgcn_mfma_f32_16x16x32_f16(
                    afa[mi], bqa[ni], acc[mi][ni], 0, 0, 0);
                acc[mi][ni] = __builtin_amdgcn_mfma_f32_16x16x32_f16(
                    afb[mi], bq2a[ni], acc[mi][ni], 0, 0, 0);
                acc[mi][ni] = __builtin_amdgcn_mfma_f32_16x16x32_f16(
                    afa[mi], bq2b[ni], acc[mi][ni], 0, 0, 0);
            }
        __builtin_amdgcn_s_setprio(0);
    }

    // ---- epilogue: scores + argmin (C/D map: col=lane&15, row=(lane>>4)*4+r) ----
    const int g = kbl, col = il;
    float nev[2];
#pragma unroll
    for (int ni = 0; ni < 2; ++ni) nev[ni] = ne[c0 + n0 + ni * 16 + col];
#pragma unroll
    for (int mi = 0; mi < 4; ++mi) {
#pragma unroll
        for (int r = 0; r < 4; ++r) {
            const int pxl = mi * 16 + g * 4 + r;
            const float nxv = nx[px0 + pxl];
            float best = 3.4e38f; int besti = 0;
#pragma unroll
            for (int ni = 0; ni < 2; ++ni) {
                float sc = (nxv + nev[ni]) - acc[mi][ni][r] * 3.90625e-03f;
                if (sc < best) { best = sc; besti = c0 + n0 + ni * 16 + col; }
            }
#pragma unroll
            for (int off = 1; off < 16; off <<= 1) {
                float ov = __shfl_xor(best, off);
                int   oi = __shfl_xor(besti, off);
                if (ov < best || (ov == best && oi < besti)) { best = ov; besti = oi; }
            }
            if (col == 0) { redV[w][pxl] = best; redI[w][pxl] = besti; }
        }
    }
    __syncthreads();
    if (t < 64) {
        float bv = redV[0][t]; int bidx = redI[0][t];
#pragma unroll
        for (int q = 1; q < 4; ++q) {
            float v = redV[q][t];
            int   i = redI[q][t];
            if (v < bv || (v == bv && i < bidx)) { bv = v; bidx = i; }
        }
        partV[cT * NPIX + px0 + t] = bv;
        partI[cT * NPIX + px0 + t] = bidx;
    }
}

// ---------------------------------------------------------------------------
// outputs2: fused {final-ids 8-way reduce, emb_st, MSE partials}.
// ---------------------------------------------------------------------------
__global__ __launch_bounds__(256) void k_outputs2(const float* __restrict__ x,
        const float* __restrict__ cb,
        const float* __restrict__ partV, const int* __restrict__ partI,
        float* __restrict__ ids_f, float* __restrict__ out_emb,
        float* __restrict__ partials)
{
    __shared__ int   ids_s[64];
    __shared__ float ev[64][65];                  // [px][c-chunk], +1 pad
    __shared__ float sm[256];

    const int t  = threadIdx.x;
    const int w  = t >> 6, l = t & 63;
    const int bi = blockIdx.x;                    // 512 = 32 b x 16 hw-tiles
    const int b  = bi >> 4;
    const int hw0 = (bi & 15) << 6;
    const int n0 = (b << 10) + hw0;               // pixel base

    if (t < 64) {                                 // final ids (lexicographic)
        const int px = n0 + t;
        float bv = partV[px]; int bix = partI[px];
#pragma unroll
        for (int ct = 1; ct < 8; ++ct) {
            float v = partV[ct * NPIX + px];
            int   i = partI[ct * NPIX + px];
            if (v < bv || (v == bv && i < bix)) { bv = v; bix = i; }
        }
        ids_f[px] = (float)bix;
        ids_s[t] = bix;
    }
    __syncthreads();

    float s = 0.f;
    for (int cc = 0; cc < 4; ++cc) {              // 4 chunks of 64 channels
#pragma unroll
        for (int pp = 0; pp < 16; ++pp) {
            const int px = w * 16 + pp;
            ev[px][l] = cb[(size_t)ids_s[px] * DIM + cc * 64 + l];
        }
        __syncthreads();
#pragma unroll
        for (int ci = 0; ci < 16; ++ci) {
            const int c  = cc * 64 + w * 16 + ci;
            const size_t xi = (((size_t)(b * DIM + c)) << 10) + hw0 + l;
            float xv = x[xi];
            float e  = ev[l][c & 63];             // stride-65 -> conflict-free
            out_emb[xi] = xv + (e - xv);
            float d = xv - e;
            s = fmaf(d, d, s);
        }
        __syncthreads();
    }
    sm[t] = s;
    __syncthreads();
    for (int off = 128; off > 0; off >>= 1) {
        if (t < off) sm[t] += sm[t + off];
        __syncthreads();
    }
    if (t == 0) partials[bi] = sm[0];
}

__global__ __launch_bounds__(256) void k_finalize(const float* __restrict__ partials,
                                                  int nparts,
                                                  float* __restrict__ out_loss)
{
    __shared__ float sm[256];
    const int tid = threadIdx.x;
    float s = 0.f;
    for (int k = tid; k < nparts; k += 256) s += partials[k];
    sm[tid] = s;
    __syncthreads();
    for (int off = 128; off > 0; off >>= 1) {
        if (tid < off) sm[tid] += sm[tid + off];
        __syncthreads();
    }
    if (tid == 0) {
        float m = sm[0] / (float)NELEM;
        out_loss[0] = m + 0.25f * m;
    }
}

// ===========================================================================
// FALLBACK (round-0 passing path, used if ws too small)
// ===========================================================================
__global__ __launch_bounds__(256) void k_enorm(const float* __restrict__ cb,
                                               float* __restrict__ enorm)
{
    const int tid  = threadIdx.x;
    const int lane = tid & 63;
    const int w    = tid >> 6;
    const int k    = blockIdx.x * 4 + w;
    const float* cp = cb + (size_t)k * DIM;
    float s = 0.f;
#pragma unroll
    for (int t = 0; t < 4; ++t) {
        float v = cp[lane + t * 64];
        s = fmaf(v, v, s);
    }
#pragma unroll
    for (int off = 32; off > 0; off >>= 1) s += __shfl_down(s, off);
    if (lane == 0) enorm[k] = s;
}

__global__ __launch_bounds__(256) void k_argmin(const float* __restrict__ x,
                                                const float* __restrict__ cb,
                                                const float* __restrict__ enorm,
                                                float* __restrict__ out_ids)
{
    __shared__ float xs[32][64];
    __shared__ float cbs[32][68];
    __shared__ float nx_l[64];
    __shared__ float nxp[4][64];
    __shared__ float red_v[64][17];
    __shared__ int   red_i[64][17];

    const int tid  = threadIdx.x;
    const int tx   = tid & 15;
    const int ty   = tid >> 4;
    const int pix0 = blockIdx.x * 64;
    const int b    = pix0 >> 10;
    const int hw0  = pix0 & 1023;

    {
        const int p = tid & 63, q = tid >> 6;
        float s = 0.f;
        const float* xp = x + ((size_t)(b * DIM + q * 64) * 1024) + hw0 + p;
        for (int c = 0; c < 64; ++c) {
            float v = xp[c * 1024];
            s = fmaf(v, v, s);
        }
        nxp[q][p] = s;
        __syncthreads();
        if (tid < 64)
            nx_l[tid] = ((nxp[0][tid] + nxp[1][tid]) + nxp[2][tid]) + nxp[3][tid];
        __syncthreads();
    }

    float nx_r[4];
#pragma unroll
    for (int i = 0; i < 4; ++i) nx_r[i] = nx_l[ty * 4 + i];

    float best_v[4];
    int   best_i[4];
#pragma unroll
    for (int i = 0; i < 4; ++i) { best_v[i] = 3.4e38f; best_i[i] = 0; }

    for (int cc = 0; cc < 16; ++cc) {
        float acc[4][4];
#pragma unroll
        for (int i = 0; i < 4; ++i)
#pragma unroll
            for (int j = 0; j < 4; ++j) acc[i][j] = 0.f;

        for (int kcc = 0; kcc < 8; ++kcc) {
            __syncthreads();
            {
                const int p = tid & 63, k0 = tid >> 6;
                const float* xp = x + ((size_t)(b * DIM + kcc * 32) * 1024) + hw0 + p;
#pragma unroll
                for (int tt = 0; tt < 8; ++tt) {
                    int kk = k0 + tt * 4;
                    xs[kk][p] = xp[kk * 1024];
                }
            }
            {
                const int kk = tid & 31, r0 = tid >> 5;
                const float* cp = cb + (size_t)(cc * 64) * DIM + kcc * 32 + kk;
#pragma unroll
                for (int tt = 0; tt < 8; ++tt) {
                    int r = r0 + tt * 8;
                    cbs[kk][r] = cp[r * DIM];
                }
            }
            __syncthreads();
#pragma unroll
            for (int kk = 0; kk < 32; ++kk) {
                float4 A = *(const float4*)&xs[kk][ty * 4];
                float4 B = *(const float4*)&cbs[kk][tx * 4];
                float a[4] = {A.x, A.y, A.z, A.w};
                float bb[4] = {B.x, B.y, B.z, B.w};
#pragma unroll
                for (int i = 0; i < 4; ++i)
#pragma unroll
                    for (int j = 0; j < 4; ++j)
                        acc[i][j] = fmaf(a[i], bb[j], acc[i][j]);
            }
        }

#pragma unroll
        for (int j = 0; j < 4; ++j) {
            const int code = cc * 64 + tx * 4 + j;
            const float nee = enorm[code];
#pragma unroll
            for (int i = 0; i < 4; ++i) {
                float s = (nx_r[i] + nee) - 2.0f * acc[i][j];
                if (s < best_v[i]) { best_v[i] = s; best_i[i] = code; }
            }
        }
    }

#pragma unroll
    for (int i = 0; i < 4; ++i) {
        red_v[ty * 4 + i][tx] = best_v[i];
        red_i[ty * 4 + i][tx] = best_i[i];
    }
    __syncthreads();
    if (tid < 64) {
        float bv = red_v[tid][0];
        int   bi = red_i[tid][0];
#pragma unroll
        for (int tt = 1; tt < 16; ++tt) {
            float v = red_v[tid][tt];
            int   idx = red_i[tid][tt];
            if (v < bv || (v == bv && idx < bi)) { bv = v; bi = idx; }
        }
        out_ids[pix0 + tid] = (float)bi;
    }
}

__global__ __launch_bounds__(256) void k_outputs(const float* __restrict__ x,
                                                 const float* __restrict__ cb,
                                                 const float* __restrict__ ids_f,
                                                 float* __restrict__ out_emb,
                                                 float* __restrict__ partials)
{
    const int tid = threadIdx.x;
    const int gid = blockIdx.x * 256 + tid;      // grid 2048
    float s = 0.f;
#pragma unroll
    for (int it = 0; it < 4; ++it) {
        const int grp = gid + it * 524288;       // float4-group index
        const int e0  = grp << 2;
        const int c   = (e0 >> 10) & 255;
        const int b   = e0 >> 18;
        const int hw  = e0 & 1023;
        const int n0  = (b << 10) + hw;
        float4 idv = *(const float4*)(ids_f + n0);
        float4 xv  = *(const float4*)(x + e0);
        float ev0 = cb[(int)idv.x * DIM + c];
        float ev1 = cb[(int)idv.y * DIM + c];
        float ev2 = cb[(int)idv.z * DIM + c];
        float ev3 = cb[(int)idv.w * DIM + c];
        float4 ov;
        ov.x = xv.x + (ev0 - xv.x);
        ov.y = xv.y + (ev1 - xv.y);
        ov.z = xv.z + (ev2 - xv.z);
        ov.w = xv.w + (ev3 - xv.w);
        *(float4*)(out_emb + e0) = ov;
        float d0 = xv.x - ev0, d1 = xv.y - ev1, d2 = xv.z - ev2, d3 = xv.w - ev3;
        s = fmaf(d0, d0, s); s = fmaf(d1, d1, s);
        s = fmaf(d2, d2, s); s = fmaf(d3, d3, s);
    }
    __shared__ float sm[256];
    sm[tid] = s;
    __syncthreads();
    for (int off = 128; off > 0; off >>= 1) {
        if (tid < off) sm[tid] += sm[tid + off];
        __syncthreads();
    }
    if (tid == 0) partials[blockIdx.x] = sm[0];
}

// ===========================================================================
extern "C" void kernel_launch(void* const* d_in, const int* in_sizes, int n_in,
                              void* d_out, int out_size, void* d_ws, size_t ws_size,
                              hipStream_t stream)
{
    const float* x  = (const float*)d_in[0];   // (32,256,32,32)
    const float* cb = (const float*)d_in[1];   // (1024,256)
    float* out   = (float*)d_out;
    float* ids_f = out;                        // 32768
    float* emb   = out + NPIX;                 // 8388608
    float* loss  = out + NPIX + NELEM;         // 1

    char* wsb = (char*)d_ws;
    const size_t NEED = 37367808ull;
    if (ws_size >= NEED) {
        u16*   Xa  = (u16*)(wsb);                    // 16 MB
        u16*   Xb  = (u16*)(wsb + 16777216);         // 16 MB
        u16*   Ea  = (u16*)(wsb + 33554432);         // 512 KB
        u16*   Ea2 = (u16*)(wsb + 34078720);         // 512 KB
        u16*   Eb2 = (u16*)(wsb + 34603008);         // 512 KB
        float* nx  = (float*)(wsb + 35127296);       // 128 KB
        float* ne  = (float*)(wsb + 35258368);       // 4 KB
        float* pV  = (float*)(wsb + 35262464);       // 1 MB
        int*   pI  = (int*)  (wsb + 36311040);       // 1 MB
        float* lp  = (float*)(wsb + 37359616);       // 8 KB
        k_prep_x    <<<512,  256, 0, stream>>>(x, Xa, Xb, nx);
        k_prep_e    <<<128,  256, 0, stream>>>(cb, Ea, Ea2, Eb2, ne);
        k_mfma_argmin<<<4096, 256, 0, stream>>>(Xa, Xb, Ea, Ea2, Eb2, nx, ne, pV, pI);
        k_outputs2  <<<512,  256, 0, stream>>>(x, cb, pV, pI, ids_f, emb, lp);
        k_finalize  <<<1,    256, 0, stream>>>(lp, 512, loss);
    } else {
        float* partials = (float*)wsb;         // 2048 floats
        float* enorm    = partials + 2048;     // 1024 floats
        k_enorm   <<<256,  256, 0, stream>>>(cb, enorm);
        k_argmin  <<<512,  256, 0, stream>>>(x, cb, enorm, ids_f);
        k_outputs <<<2048, 256, 0, stream>>>(x, cb, ids_f, emb, partials);
        k_finalize<<<1,    256, 0, stream>>>(partials, 2048, loss);
    }
}

// Round 17
// 107.526 us; speedup vs baseline: 1.0437x; 1.0437x over previous
//
#include <hip/hip_runtime.h>

#define NUM_EMB 1024
#define DIM     256
#define NPIX    32768      // 32 * 32 * 32
#define NELEM   8388608    // 32 * 256 * 32 * 32

typedef unsigned short u16;
typedef unsigned int   u32;
typedef __attribute__((ext_vector_type(8))) _Float16 f16x8;
typedef __attribute__((ext_vector_type(4))) float f32x4;

__device__ __forceinline__ u16 f32_f16(float f) {
    _Float16 h = (_Float16)f;                  // v_cvt_f16_f32, RN-even
    return __builtin_bit_cast(u16, h);
}
__device__ __forceinline__ float f16_f32(u16 b) {
    return (float)__builtin_bit_cast(_Float16, b);
}

// ===========================================================================
// MFMA path — f16 2-term split, SINGLE-accumulator 3-pair formulation:
//   x = 4*(Xa + 2^-10*Xb + eps), e = 2^-11*(Ea + 2^-10*Eb + eps)
//   pre-scaled B operands: Ea2 = f16(Ea*2^-10), Eb2 = f16(Eb*2^-10)
//   acc += Xa*Ea + Xb*Ea2 + Xa*Eb2  =>  2*x*e = 2^-8 * acc
// ===========================================================================

// ---------------------------------------------------------------------------
// k_prep: merged {prep_x (blocks 0..511), prep_e (blocks 512..639)}.
// prep_x: split x -> Xa,Xb f16 frag-major [kc8][kb4][px][8k]; |x|^2/pixel.
// prep_e: split cb -> Ea, Ea2=Ea*2^-10, Eb2=Eb*2^-10 frag-major; |e|^2/code.
// Bodies identical to the r15-verified kernels; branch is block-uniform.
// ---------------------------------------------------------------------------
__global__ __launch_bounds__(256) void k_prep(const float* __restrict__ x,
        const float* __restrict__ cb,
        u16* __restrict__ Xa, u16* __restrict__ Xb,
        u16* __restrict__ Ea, u16* __restrict__ Ea2, u16* __restrict__ Eb2,
        float* __restrict__ nx_out, float* __restrict__ ne_out)
{
    __shared__ float nxp[4][64];
    const int t  = threadIdx.x;
    const int bi = blockIdx.x;                 // 640

    if (bi < 512) {
        // ---- prep_x ----
        const int p  = t & 63;
        const int cq = t >> 6;
        const int b  = bi >> 4;
        const int hw = ((bi & 15) << 6) + p;
        const float* xp = x + (((size_t)(b * 256 + cq * 64)) << 10) + hw;
        float s = 0.f;
        for (int i0 = 0; i0 < 64; i0 += 8) {
            u32 qa[4], qb[4];
#pragma unroll
            for (int j = 0; j < 8; ++j) {
                float v = xp[(size_t)(i0 + j) << 10];
                s = fmaf(v, v, s);
                float va = v * 0.25f;                  // exact
                u16 ha = f32_f16(va);
                float rb = (va - f16_f32(ha)) * 1024.0f;   // exact (Sterbenz+pow2)
                u16 hb = f32_f16(rb);
                if ((j & 1) == 0) { qa[j>>1] = ha; qb[j>>1] = hb; }
                else { qa[j>>1] |= (u32)ha << 16; qb[j>>1] |= (u32)hb << 16; }
            }
            const int c = cq * 64 + i0;
            const size_t chunk = (((size_t)((c >> 5) * 4 + ((c >> 3) & 3))) << 15)
                                 + (size_t)bi * 64 + p;
            *(uint4*)(Xa + chunk * 8) = make_uint4(qa[0], qa[1], qa[2], qa[3]);
            *(uint4*)(Xb + chunk * 8) = make_uint4(qb[0], qb[1], qb[2], qb[3]);
        }
        nxp[cq][p] = s;
        __syncthreads();
        if (t < 64)
            nx_out[bi * 64 + t] = ((nxp[0][t] + nxp[1][t]) + nxp[2][t]) + nxp[3][t];
    } else {
        // ---- prep_e ----
        const int bi2 = bi - 512;              // 0..127
        const int l32 = t & 31;
        const int code = bi2 * 8 + (t >> 5);
        const float* cp = cb + (size_t)code * 256 + l32 * 8;
        u32 qa[4], qa2[4], qb2[4];
        float s = 0.f;
#pragma unroll
        for (int j = 0; j < 8; ++j) {
            float v = cp[j];
            s = fmaf(v, v, s);
            float va = v * 2048.0f;                    // exact
            u16 ha = f32_f16(va);
            float rb = (va - f16_f32(ha)) * 1024.0f;   // exact
            u16 hb = f32_f16(rb);
            u16 ha2 = f32_f16(f16_f32(ha) * 9.765625e-04f);  // Ea*2^-10
            u16 hb2 = f32_f16(f16_f32(hb) * 9.765625e-04f);  // Eb*2^-10
            if ((j & 1) == 0) { qa[j>>1] = ha; qa2[j>>1] = ha2; qb2[j>>1] = hb2; }
            else { qa[j>>1] |= (u32)ha << 16; qa2[j>>1] |= (u32)ha2 << 16; qb2[j>>1] |= (u32)hb2 << 16; }
        }
        const size_t chunk = ((size_t)l32 << 10) + code;
        *(uint4*)(Ea  + chunk * 8) = make_uint4(qa[0],  qa[1],  qa[2],  qa[3]);
        *(uint4*)(Ea2 + chunk * 8) = make_uint4(qa2[0], qa2[1], qa2[2], qa2[3]);
        *(uint4*)(Eb2 + chunk * 8) = make_uint4(qb2[0], qb2[1], qb2[2], qb2[3]);
#pragma unroll
        for (int off = 16; off > 0; off >>= 1) s += __shfl_xor(s, off);
        if (l32 == 0) ne_out[code] = s;
    }
}

// ---------------------------------------------------------------------------
// MFMA distance-argmin. Round-17 = r12 ring-4 counted-vmcnt schedule x
// r15 single-acc math (both independently verified, absmax 0):
//   - block 256 thr / 4 waves; tile 64px x 128codes; wave = 64px x 32codes
//   - A staged via global_load_lds into a RING of 4 buffers, 2 kc ahead;
//     ONE s_barrier per kc with vmcnt(2) — stage(kc+2) rides the barrier.
//     B (Ea,Ea2,Eb2) reg-loads issued FIRST each kc (FIFO-oldest), so the
//     compiler's pre-MFMA B-wait lands at vmcnt(2), stages keep flying.
//   - ring distance-2 write/read + 1 barrier/kc (skew<=1) => race-free.
//   - acc = 8 x f32x4 = 32 AGPR; ~48-64 VGPR -> launch_bounds(256,5).
//   - same per-acc MFMA order as r15/r16 -> bit-identical scores.
// ---------------------------------------------------------------------------
__global__ __launch_bounds__(256, 5) void k_mfma_argmin(
        const u16* __restrict__ XA, const u16* __restrict__ XB,
        const u16* __restrict__ EA, const u16* __restrict__ EA2,
        const u16* __restrict__ EB2,
        const float* __restrict__ nx, const float* __restrict__ ne,
        float* __restrict__ partV, int* __restrict__ partI)
{
    __shared__ __align__(16) unsigned char ldsA[4][8192];  // ring of 4
    __shared__ float redV[4][64];
    __shared__ int   redI[4][64];

    const int t = threadIdx.x;
    const int l = t & 63;
    const int w = t >> 6;

    // XCD-aware bijective swizzle (grid 4096 % 8 == 0)
    const int bi   = blockIdx.x;
    const int xcd  = bi & 7;
    const int slot = bi >> 3;
    const int cT   = slot & 7;
    const int pT   = ((slot >> 3) << 3) | xcd;     // [0, 512)
    const int px0  = pT << 6;                      // 64-px tile
    const int c0   = cT << 7;                      // 128-code tile
    const int n0   = w << 5;                       // wave owns 32 codes
    const int kbl  = l >> 4;
    const int il   = l & 15;

    const u16* Xt[2] = {XA, XB};

    // stage A tile for K-step kc: 2 terms x 64px x 32d x 2B = 8KB, 2 ops/thr
    auto stageA = [&](int kc, int bf) {
#pragma unroll
        for (int q = 0; q < 2; ++q) {
            const int kb = t >> 6, px = t & 63;
            const u16* sa = Xt[q] + ((((size_t)(kc * 4 + kb)) << 15) + px0 + px) * 8;
            __builtin_amdgcn_global_load_lds(
                (const __attribute__((address_space(1))) void*)sa,
                (__attribute__((address_space(3))) void*)(&ldsA[bf][q * 4096 + t * 16]),
                16, 0, 0);
        }
    };

    f32x4 acc[4][2];
#pragma unroll
    for (int i = 0; i < 4; ++i)
#pragma unroll
        for (int j = 0; j < 2; ++j) acc[i][j] = (f32x4){0.f, 0.f, 0.f, 0.f};

    const size_t boff = (size_t)kbl * 8192 + (size_t)(c0 + n0 + il) * 8;
    const u16* pBa  = EA  + boff;
    const u16* pBa2 = EA2 + boff;
    const u16* pBb2 = EB2 + boff;

    // ---- prologue: stage kc=0,1 into b0,b1; wait b0 only (b1 flies) ----
    stageA(0, 0);
    stageA(1, 1);
    __builtin_amdgcn_sched_barrier(0);
    asm volatile("s_waitcnt vmcnt(2)" ::: "memory");
    __builtin_amdgcn_s_barrier();
    __builtin_amdgcn_sched_barrier(0);

#pragma unroll
    for (int kc = 0; kc < 8; ++kc) {
        const int bf = kc & 3;

        // B fragments for kc: issued FIRST so stage(kc+2) is FIFO-newest
        f16x8 bqa[2], bq2a[2], bq2b[2];
#pragma unroll
        for (int ni = 0; ni < 2; ++ni) {
            const size_t o = (size_t)kc * 32768 + ni * 128;
            bqa[ni]  = *(const f16x8*)(pBa  + o);
            bq2a[ni] = *(const f16x8*)(pBa2 + o);
            bq2b[ni] = *(const f16x8*)(pBb2 + o);
        }
        if (kc < 6) stageA(kc + 2, (kc + 2) & 3);  // 2-ahead ring refill

        __builtin_amdgcn_s_setprio(1);
#pragma unroll
        for (int mi = 0; mi < 4; ++mi) {
            const int fo = (kbl * 64 + mi * 16 + il) * 16;
            f16x8 afa = *(const f16x8*)(&ldsA[bf][fo]);
            f16x8 afb = *(const f16x8*)(&ldsA[bf][4096 + fo]);
#pragma unroll
            for (int ni = 0; ni < 2; ++ni) {
                acc[mi][ni] = __builtin_amdgcn_mfma_f32_16x16x32_f16(
                    afa, bqa[ni], acc[mi][ni], 0, 0, 0);
                acc[mi][ni] = __builtin_amdgcn_mfma_f32_16x16x32_f16(
                    afb, bq2a[ni], acc[mi][ni], 0, 0, 0);
                acc[mi][ni] = __builtin_amdgcn_mfma_f32_16x16x32_f16(
                    afa, bq2b[ni], acc[mi][ni], 0, 0, 0);
            }
        }
        __builtin_amdgcn_s_setprio(0);

        if (kc < 7) {
            // counted wait: stage(kc+1) landed; stage(kc+2) stays in flight
            __builtin_amdgcn_sched_barrier(0);
            if (kc < 6)
                asm volatile("s_waitcnt vmcnt(2)" ::: "memory");
            else
                asm volatile("s_waitcnt vmcnt(0)" ::: "memory");
            __builtin_amdgcn_s_barrier();
            __builtin_amdgcn_sched_barrier(0);
        }
    }

    // ---- epilogue: scores + argmin (C/D map: col=lane&15, row=(lane>>4)*4+r) ----
    const int g = kbl, col = il;
    float nev[2];
#pragma unroll
    for (int ni = 0; ni < 2; ++ni) nev[ni] = ne[c0 + n0 + ni * 16 + col];
#pragma unroll
    for (int mi = 0; mi < 4; ++mi) {
#pragma unroll
        for (int r = 0; r < 4; ++r) {
            const int pxl = mi * 16 + g * 4 + r;
            const float nxv = nx[px0 + pxl];
            float best = 3.4e38f; int besti = 0;
#pragma unroll
            for (int ni = 0; ni < 2; ++ni) {
                float sc = (nxv + nev[ni]) - acc[mi][ni][r] * 3.90625e-03f;
                if (sc < best) { best = sc; besti = c0 + n0 + ni * 16 + col; }
            }
#pragma unroll
            for (int off = 1; off < 16; off <<= 1) {
                float ov = __shfl_xor(best, off);
                int   oi = __shfl_xor(besti, off);
                if (ov < best || (ov == best && oi < besti)) { best = ov; besti = oi; }
            }
            if (col == 0) { redV[w][pxl] = best; redI[w][pxl] = besti; }
        }
    }
    __syncthreads();
    if (t < 64) {
        float bv = redV[0][t]; int bidx = redI[0][t];
#pragma unroll
        for (int q = 1; q < 4; ++q) {
            float v = redV[q][t];
            int   i = redI[q][t];
            if (v < bv || (v == bv && i < bidx)) { bv = v; bidx = i; }
        }
        partV[cT * NPIX + px0 + t] = bv;
        partI[cT * NPIX + px0 + t] = bidx;
    }
}

// ---------------------------------------------------------------------------
// outputs2: fused {final-ids 8-way reduce, emb_st, MSE partials}.
// ---------------------------------------------------------------------------
__global__ __launch_bounds__(256) void k_outputs2(const float* __restrict__ x,
        const float* __restrict__ cb,
        const float* __restrict__ partV, const int* __restrict__ partI,
        float* __restrict__ ids_f, float* __restrict__ out_emb,
        float* __restrict__ partials)
{
    __shared__ int   ids_s[64];
    __shared__ float ev[64][65];                  // [px][c-chunk], +1 pad
    __shared__ float sm[256];

    const int t  = threadIdx.x;
    const int w  = t >> 6, l = t & 63;
    const int bi = blockIdx.x;                    // 512 = 32 b x 16 hw-tiles
    const int b  = bi >> 4;
    const int hw0 = (bi & 15) << 6;
    const int n0 = (b << 10) + hw0;               // pixel base

    if (t < 64) {                                 // final ids (lexicographic)
        const int px = n0 + t;
        float bv = partV[px]; int bix = partI[px];
#pragma unroll
        for (int ct = 1; ct < 8; ++ct) {
            float v = partV[ct * NPIX + px];
            int   i = partI[ct * NPIX + px];
            if (v < bv || (v == bv && i < bix)) { bv = v; bix = i; }
        }
        ids_f[px] = (float)bix;
        ids_s[t] = bix;
    }
    __syncthreads();

    float s = 0.f;
    for (int cc = 0; cc < 4; ++cc) {              // 4 chunks of 64 channels
#pragma unroll
        for (int pp = 0; pp < 16; ++pp) {
            const int px = w * 16 + pp;
            ev[px][l] = cb[(size_t)ids_s[px] * DIM + cc * 64 + l];
        }
        __syncthreads();
#pragma unroll
        for (int ci = 0; ci < 16; ++ci) {
            const int c  = cc * 64 + w * 16 + ci;
            const size_t xi = (((size_t)(b * DIM + c)) << 10) + hw0 + l;
            float xv = x[xi];
            float e  = ev[l][c & 63];             // stride-65 -> conflict-free
            out_emb[xi] = xv + (e - xv);
            float d = xv - e;
            s = fmaf(d, d, s);
        }
        __syncthreads();
    }
    sm[t] = s;
    __syncthreads();
    for (int off = 128; off > 0; off >>= 1) {
        if (t < off) sm[t] += sm[t + off];
        __syncthreads();
    }
    if (t == 0) partials[bi] = sm[0];
}

__global__ __launch_bounds__(256) void k_finalize(const float* __restrict__ partials,
                                                  int nparts,
                                                  float* __restrict__ out_loss)
{
    __shared__ float sm[256];
    const int tid = threadIdx.x;
    float s = 0.f;
    for (int k = tid; k < nparts; k += 256) s += partials[k];
    sm[tid] = s;
    __syncthreads();
    for (int off = 128; off > 0; off >>= 1) {
        if (tid < off) sm[tid] += sm[tid + off];
        __syncthreads();
    }
    if (tid == 0) {
        float m = sm[0] / (float)NELEM;
        out_loss[0] = m + 0.25f * m;
    }
}

// ===========================================================================
// FALLBACK (round-0 passing path, used if ws too small)
// ===========================================================================
__global__ __launch_bounds__(256) void k_enorm(const float* __restrict__ cb,
                                               float* __restrict__ enorm)
{
    const int tid  = threadIdx.x;
    const int lane = tid & 63;
    const int w    = tid >> 6;
    const int k    = blockIdx.x * 4 + w;
    const float* cp = cb + (size_t)k * DIM;
    float s = 0.f;
#pragma unroll
    for (int t = 0; t < 4; ++t) {
        float v = cp[lane + t * 64];
        s = fmaf(v, v, s);
    }
#pragma unroll
    for (int off = 32; off > 0; off >>= 1) s += __shfl_down(s, off);
    if (lane == 0) enorm[k] = s;
}

__global__ __launch_bounds__(256) void k_argmin(const float* __restrict__ x,
                                                const float* __restrict__ cb,
                                                const float* __restrict__ enorm,
                                                float* __restrict__ out_ids)
{
    __shared__ float xs[32][64];
    __shared__ float cbs[32][68];
    __shared__ float nx_l[64];
    __shared__ float nxp[4][64];
    __shared__ float red_v[64][17];
    __shared__ int   red_i[64][17];

    const int tid  = threadIdx.x;
    const int tx   = tid & 15;
    const int ty   = tid >> 4;
    const int pix0 = blockIdx.x * 64;
    const int b    = pix0 >> 10;
    const int hw0  = pix0 & 1023;

    {
        const int p = tid & 63, q = tid >> 6;
        float s = 0.f;
        const float* xp = x + ((size_t)(b * DIM + q * 64) * 1024) + hw0 + p;
        for (int c = 0; c < 64; ++c) {
            float v = xp[c * 1024];
            s = fmaf(v, v, s);
        }
        nxp[q][p] = s;
        __syncthreads();
        if (tid < 64)
            nx_l[tid] = ((nxp[0][tid] + nxp[1][tid]) + nxp[2][tid]) + nxp[3][tid];
        __syncthreads();
    }

    float nx_r[4];
#pragma unroll
    for (int i = 0; i < 4; ++i) nx_r[i] = nx_l[ty * 4 + i];

    float best_v[4];
    int   best_i[4];
#pragma unroll
    for (int i = 0; i < 4; ++i) { best_v[i] = 3.4e38f; best_i[i] = 0; }

    for (int cc = 0; cc < 16; ++cc) {
        float acc[4][4];
#pragma unroll
        for (int i = 0; i < 4; ++i)
#pragma unroll
            for (int j = 0; j < 4; ++j) acc[i][j] = 0.f;

        for (int kcc = 0; kcc < 8; ++kcc) {
            __syncthreads();
            {
                const int p = tid & 63, k0 = tid >> 6;
                const float* xp = x + ((size_t)(b * DIM + kcc * 32) * 1024) + hw0 + p;
#pragma unroll
                for (int tt = 0; tt < 8; ++tt) {
                    int kk = k0 + tt * 4;
                    xs[kk][p] = xp[kk * 1024];
                }
            }
            {
                const int kk = tid & 31, r0 = tid >> 5;
                const float* cp = cb + (size_t)(cc * 64) * DIM + kcc * 32 + kk;
#pragma unroll
                for (int tt = 0; tt < 8; ++tt) {
                    int r = r0 + tt * 8;
                    cbs[kk][r] = cp[r * DIM];
                }
            }
            __syncthreads();
#pragma unroll
            for (int kk = 0; kk < 32; ++kk) {
                float4 A = *(const float4*)&xs[kk][ty * 4];
                float4 B = *(const float4*)&cbs[kk][tx * 4];
                float a[4] = {A.x, A.y, A.z, A.w};
                float bb[4] = {B.x, B.y, B.z, B.w};
#pragma unroll
                for (int i = 0; i < 4; ++i)
#pragma unroll
                    for (int j = 0; j < 4; ++j)
                        acc[i][j] = fmaf(a[i], bb[j], acc[i][j]);
            }
        }

#pragma unroll
        for (int j = 0; j < 4; ++j) {
            const int code = cc * 64 + tx * 4 + j;
            const float nee = enorm[code];
#pragma unroll
            for (int i = 0; i < 4; ++i) {
                float s = (nx_r[i] + nee) - 2.0f * acc[i][j];
                if (s < best_v[i]) { best_v[i] = s; best_i[i] = code; }
            }
        }
    }

#pragma unroll
    for (int i = 0; i < 4; ++i) {
        red_v[ty * 4 + i][tx] = best_v[i];
        red_i[ty * 4 + i][tx] = best_i[i];
    }
    __syncthreads();
    if (tid < 64) {
        float bv = red_v[tid][0];
        int   bi = red_i[tid][0];
#pragma unroll
        for (int tt = 1; tt < 16; ++tt) {
            float v = red_v[tid][tt];
            int   idx = red_i[tid][tt];
            if (v < bv || (v == bv && idx < bi)) { bv = v; bi = idx; }
        }
        out_ids[pix0 + tid] = (float)bi;
    }
}

__global__ __launch_bounds__(256) void k_outputs(const float* __restrict__ x,
                                                 const float* __restrict__ cb,
                                                 const float* __restrict__ ids_f,
                                                 float* __restrict__ out_emb,
                                                 float* __restrict__ partials)
{
    const int tid = threadIdx.x;
    const int gid = blockIdx.x * 256 + tid;      // grid 2048
    float s = 0.f;
#pragma unroll
    for (int it = 0; it < 4; ++it) {
        const int grp = gid + it * 524288;       // float4-group index
        const int e0  = grp << 2;
        const int c   = (e0 >> 10) & 255;
        const int b   = e0 >> 18;
        const int hw  = e0 & 1023;
        const int n0  = (b << 10) + hw;
        float4 idv = *(const float4*)(ids_f + n0);
        float4 xv  = *(const float4*)(x + e0);
        float ev0 = cb[(int)idv.x * DIM + c];
        float ev1 = cb[(int)idv.y * DIM + c];
        float ev2 = cb[(int)idv.z * DIM + c];
        float ev3 = cb[(int)idv.w * DIM + c];
        float4 ov;
        ov.x = xv.x + (ev0 - xv.x);
        ov.y = xv.y + (ev1 - xv.y);
        ov.z = xv.z + (ev2 - xv.z);
        ov.w = xv.w + (ev3 - xv.w);
        *(float4*)(out_emb + e0) = ov;
        float d0 = xv.x - ev0, d1 = xv.y - ev1, d2 = xv.z - ev2, d3 = xv.w - ev3;
        s = fmaf(d0, d0, s); s = fmaf(d1, d1, s);
        s = fmaf(d2, d2, s); s = fmaf(d3, d3, s);
    }
    __shared__ float sm[256];
    sm[tid] = s;
    __syncthreads();
    for (int off = 128; off > 0; off >>= 1) {
        if (tid < off) sm[tid] += sm[tid + off];
        __syncthreads();
    }
    if (tid == 0) partials[blockIdx.x] = sm[0];
}

// ===========================================================================
extern "C" void kernel_launch(void* const* d_in, const int* in_sizes, int n_in,
                              void* d_out, int out_size, void* d_ws, size_t ws_size,
                              hipStream_t stream)
{
    const float* x  = (const float*)d_in[0];   // (32,256,32,32)
    const float* cb = (const float*)d_in[1];   // (1024,256)
    float* out   = (float*)d_out;
    float* ids_f = out;                        // 32768
    float* emb   = out + NPIX;                 // 8388608
    float* loss  = out + NPIX + NELEM;         // 1

    char* wsb = (char*)d_ws;
    const size_t NEED = 37367808ull;
    if (ws_size >= NEED) {
        u16*   Xa  = (u16*)(wsb);                    // 16 MB
        u16*   Xb  = (u16*)(wsb + 16777216);         // 16 MB
        u16*   Ea  = (u16*)(wsb + 33554432);         // 512 KB
        u16*   Ea2 = (u16*)(wsb + 34078720);         // 512 KB
        u16*   Eb2 = (u16*)(wsb + 34603008);         // 512 KB
        float* nx  = (float*)(wsb + 35127296);       // 128 KB
        float* ne  = (float*)(wsb + 35258368);       // 4 KB
        float* pV  = (float*)(wsb + 35262464);       // 1 MB
        int*   pI  = (int*)  (wsb + 36311040);       // 1 MB
        float* lp  = (float*)(wsb + 37359616);       // 8 KB
        k_prep      <<<640,  256, 0, stream>>>(x, cb, Xa, Xb, Ea, Ea2, Eb2, nx, ne);
        k_mfma_argmin<<<4096, 256, 0, stream>>>(Xa, Xb, Ea, Ea2, Eb2, nx, ne, pV, pI);
        k_outputs2  <<<512,  256, 0, stream>>>(x, cb, pV, pI, ids_f, emb, lp);
        k_finalize  <<<1,    256, 0, stream>>>(lp, 512, loss);
    } else {
        float* partials = (float*)wsb;         // 2048 floats
        float* enorm    = partials + 2048;     // 1024 floats
        k_enorm   <<<256,  256, 0, stream>>>(cb, enorm);
        k_argmin  <<<512,  256, 0, stream>>>(x, cb, enorm, ids_f);
        k_outputs <<<2048, 256, 0, stream>>>(x, cb, ids_f, emb, partials);
        k_finalize<<<1,    256, 0, stream>>>(partials, 2048, loss);
    }
}

// Round 18
// 105.454 us; speedup vs baseline: 1.0642x; 1.0196x over previous
//
#include <hip/hip_runtime.h>

#define NUM_EMB 1024
#define DIM     256
#define NPIX    32768      // 32 * 32 * 32
#define NELEM   8388608    // 32 * 256 * 32 * 32

typedef unsigned short u16;
typedef unsigned int   u32;
typedef __attribute__((ext_vector_type(8))) _Float16 f16x8;
typedef __attribute__((ext_vector_type(4))) float f32x4;

__device__ __forceinline__ u16 f32_f16(float f) {
    _Float16 h = (_Float16)f;                  // v_cvt_f16_f32, RN-even
    return __builtin_bit_cast(u16, h);
}
__device__ __forceinline__ float f16_f32(u16 b) {
    return (float)__builtin_bit_cast(_Float16, b);
}

// ===========================================================================
// MFMA path — f16 2-term split, 2 scale groups, 3 MFMA term-pairs.
//   x = 4*(Xa + 2^-10*Xb + eps), e = 2^-11*(Ea + 2^-10*Eb + eps)
//   2*x*e = 2^-8 * [S_aa + 2^-10*(S_ab + S_ba)]   (S_bb dropped, ~5e-9)
// ===========================================================================

// ---------------------------------------------------------------------------
// prep_x: split x into Xa,Xb f16 arrays, frag-major [kc8][kb4][px][8k];
// |x|^2 per pixel.
// ---------------------------------------------------------------------------
__global__ __launch_bounds__(256) void k_prep_x(const float* __restrict__ x,
        u16* __restrict__ Xa, u16* __restrict__ Xb,
        float* __restrict__ nx_out)
{
    __shared__ float nxp[4][64];
    const int t  = threadIdx.x;
    const int p  = t & 63;
    const int cq = t >> 6;
    const int bi = blockIdx.x;            // 512
    const int b  = bi >> 4;
    const int hw = ((bi & 15) << 6) + p;
    const float* xp = x + (((size_t)(b * 256 + cq * 64)) << 10) + hw;
    float s = 0.f;
    for (int i0 = 0; i0 < 64; i0 += 8) {
        u32 qa[4], qb[4];
#pragma unroll
        for (int j = 0; j < 8; ++j) {
            float v = xp[(size_t)(i0 + j) << 10];
            s = fmaf(v, v, s);
            float va = v * 0.25f;                  // exact
            u16 ha = f32_f16(va);
            float rb = (va - f16_f32(ha)) * 1024.0f;   // exact (Sterbenz + pow2)
            u16 hb = f32_f16(rb);
            if ((j & 1) == 0) { qa[j>>1] = ha; qb[j>>1] = hb; }
            else { qa[j>>1] |= (u32)ha << 16; qb[j>>1] |= (u32)hb << 16; }
        }
        const int c = cq * 64 + i0;
        const size_t chunk = (((size_t)((c >> 5) * 4 + ((c >> 3) & 3))) << 15)
                             + (size_t)bi * 64 + p;
        *(uint4*)(Xa + chunk * 8) = make_uint4(qa[0], qa[1], qa[2], qa[3]);
        *(uint4*)(Xb + chunk * 8) = make_uint4(qb[0], qb[1], qb[2], qb[3]);
    }
    nxp[cq][p] = s;
    __syncthreads();
    if (t < 64)
        nx_out[bi * 64 + t] = ((nxp[0][t] + nxp[1][t]) + nxp[2][t]) + nxp[3][t];
}

// ---------------------------------------------------------------------------
// prep_e: same split for codebook -> [kc][kb][code(1024)][8k] + |e|^2
// ---------------------------------------------------------------------------
__global__ __launch_bounds__(256) void k_prep_e(const float* __restrict__ cb,
        u16* __restrict__ Ea, u16* __restrict__ Eb,
        float* __restrict__ ne_out)
{
    const int t = threadIdx.x;
    const int l32 = t & 31;
    const int code = blockIdx.x * 8 + (t >> 5);
    const float* cp = cb + (size_t)code * 256 + l32 * 8;
    u32 qa[4], qb[4];
    float s = 0.f;
#pragma unroll
    for (int j = 0; j < 8; ++j) {
        float v = cp[j];
        s = fmaf(v, v, s);
        float va = v * 2048.0f;                    // exact
        u16 ha = f32_f16(va);
        float rb = (va - f16_f32(ha)) * 1024.0f;   // exact
        u16 hb = f32_f16(rb);
        if ((j & 1) == 0) { qa[j>>1] = ha; qb[j>>1] = hb; }
        else { qa[j>>1] |= (u32)ha << 16; qb[j>>1] |= (u32)hb << 16; }
    }
    const size_t chunk = ((size_t)l32 << 10) + code;
    *(uint4*)(Ea + chunk * 8) = make_uint4(qa[0], qa[1], qa[2], qa[3]);
    *(uint4*)(Eb + chunk * 8) = make_uint4(qb[0], qb[1], qb[2], qb[3]);
#pragma unroll
    for (int off = 16; off > 0; off >>= 1) s += __shfl_xor(s, off);
    if (l32 == 0) ne_out[code] = s;
}

// ---------------------------------------------------------------------------
// MFMA distance-argmin. Session-best (round-12) configuration:
//   - block 256 thr / 4 waves; tile 64px x 128codes; wave = 64px x 32codes
//   - A staged via global_load_lds into a RING of 4 buffers, 2 kc ahead.
//   - ONE s_barrier per kc with vmcnt(2) (counted, not drain-0): stage(kc+2)'s
//     2 loads stay in flight across the barrier (T4). B reg-loads are issued
//     BEFORE the stage so the compiler's own B-wait lands at vmcnt(2) too.
//   - ring distance-2 write vs read + 1 barrier/kc (skew<=1) => race-free.
//   - launch_bounds(256,4): 64 VGPR + 64 AGPR = 128/thread is the budget.
//   - f16 3-pair math, per-acc MFMA order fixed -> verified absmax 0.
// ---------------------------------------------------------------------------
__global__ __launch_bounds__(256, 4) void k_mfma_argmin(
        const u16* __restrict__ XA, const u16* __restrict__ XB,
        const u16* __restrict__ EA, const u16* __restrict__ EB,
        const float* __restrict__ nx, const float* __restrict__ ne,
        float* __restrict__ partV, int* __restrict__ partI)
{
    __shared__ __align__(16) unsigned char ldsA[4][8192];  // ring of 4
    __shared__ float redV[4][64];
    __shared__ int   redI[4][64];

    const int t = threadIdx.x;
    const int l = t & 63;
    const int w = t >> 6;

    // XCD-aware bijective swizzle (grid 4096 % 8 == 0)
    const int bi   = blockIdx.x;
    const int xcd  = bi & 7;
    const int slot = bi >> 3;
    const int cT   = slot & 7;
    const int pT   = ((slot >> 3) << 3) | xcd;     // [0, 512)
    const int px0  = pT << 6;                      // 64-px tile
    const int c0   = cT << 7;                      // 128-code tile
    const int n0   = w << 5;                       // wave owns 32 codes
    const int kbl  = l >> 4;
    const int il   = l & 15;

    const u16* Xt[2] = {XA, XB};

    // stage A tile for K-step kc: 2 terms x 64px x 32d x 2B = 8KB, 2 ops/thr
    auto stageA = [&](int kc, int bf) {
#pragma unroll
        for (int q = 0; q < 2; ++q) {
            const int kb = t >> 6, px = t & 63;
            const u16* sa = Xt[q] + ((((size_t)(kc * 4 + kb)) << 15) + px0 + px) * 8;
            __builtin_amdgcn_global_load_lds(
                (const __attribute__((address_space(1))) void*)sa,
                (__attribute__((address_space(3))) void*)(&ldsA[bf][q * 4096 + t * 16]),
                16, 0, 0);
        }
    };

    f32x4 acc1[4][2], acc2[4][2];
#pragma unroll
    for (int i = 0; i < 4; ++i)
#pragma unroll
        for (int j = 0; j < 2; ++j) {
            acc1[i][j] = (f32x4){0.f, 0.f, 0.f, 0.f};
            acc2[i][j] = (f32x4){0.f, 0.f, 0.f, 0.f};
        }

    const size_t boff = (size_t)kbl * 8192 + (size_t)(c0 + n0 + il) * 8;
    const u16* pBa = EA + boff;
    const u16* pBb = EB + boff;

    // ---- prologue: stage kc=0,1 into b0,b1; wait b0 only (b1 flies) ----
    stageA(0, 0);
    stageA(1, 1);
    __builtin_amdgcn_sched_barrier(0);
    asm volatile("s_waitcnt vmcnt(2)" ::: "memory");
    __builtin_amdgcn_s_barrier();
    __builtin_amdgcn_sched_barrier(0);

#pragma unroll
    for (int kc = 0; kc < 8; ++kc) {
        const int bf = kc & 3;

        // B fragments for kc: issued FIRST so stage(kc+2) is FIFO-newest;
        // compiler's pre-MFMA wait for B then = vmcnt(2), stages keep flying.
        f16x8 bqa[2], bqb[2];
#pragma unroll
        for (int ni = 0; ni < 2; ++ni) {
            bqa[ni] = *(const f16x8*)(pBa + (size_t)kc * 32768 + ni * 128);
            bqb[ni] = *(const f16x8*)(pBb + (size_t)kc * 32768 + ni * 128);
        }
        if (kc < 6) stageA(kc + 2, (kc + 2) & 3);  // 2-ahead ring refill

        __builtin_amdgcn_s_setprio(1);
#pragma unroll
        for (int mi = 0; mi < 4; ++mi) {
            const int fo = (kbl * 64 + mi * 16 + il) * 16;
            f16x8 afa = *(const f16x8*)(&ldsA[bf][fo]);
            f16x8 afb = *(const f16x8*)(&ldsA[bf][4096 + fo]);
#pragma unroll
            for (int ni = 0; ni < 2; ++ni) {
                acc1[mi][ni] = __builtin_amdgcn_mfma_f32_16x16x32_f16(
                    afa, bqa[ni], acc1[mi][ni], 0, 0, 0);
                acc2[mi][ni] = __builtin_amdgcn_mfma_f32_16x16x32_f16(
                    afb, bqa[ni], acc2[mi][ni], 0, 0, 0);
                acc2[mi][ni] = __builtin_amdgcn_mfma_f32_16x16x32_f16(
                    afa, bqb[ni], acc2[mi][ni], 0, 0, 0);
            }
        }
        __builtin_amdgcn_s_setprio(0);

        if (kc < 7) {
            // counted wait: ensure stage(kc+1) landed; stage(kc+2) stays in flight
            __builtin_amdgcn_sched_barrier(0);
            if (kc < 6)
                asm volatile("s_waitcnt vmcnt(2)" ::: "memory");
            else
                asm volatile("s_waitcnt vmcnt(0)" ::: "memory");
            __builtin_amdgcn_s_barrier();
            __builtin_amdgcn_sched_barrier(0);
        }
    }

    // ---- epilogue: scores + argmin (C/D map: col=lane&15, row=(lane>>4)*4+r) ----
    const int g = kbl, col = il;
    float nev[2];
#pragma unroll
    for (int ni = 0; ni < 2; ++ni) nev[ni] = ne[c0 + n0 + ni * 16 + col];
#pragma unroll
    for (int mi = 0; mi < 4; ++mi) {
#pragma unroll
        for (int r = 0; r < 4; ++r) {
            const int pxl = mi * 16 + g * 4 + r;
            const float nxv = nx[px0 + pxl];
            float best = 3.4e38f; int besti = 0;
#pragma unroll
            for (int ni = 0; ni < 2; ++ni) {
                float tt = fmaf(acc2[mi][ni][r], 9.765625e-04f, acc1[mi][ni][r]);
                float sc = (nxv + nev[ni]) - tt * 3.90625e-03f;  // pow2 scale exact
                if (sc < best) { best = sc; besti = c0 + n0 + ni * 16 + col; }
            }
#pragma unroll
            for (int off = 1; off < 16; off <<= 1) {
                float ov = __shfl_xor(best, off);
                int   oi = __shfl_xor(besti, off);
                if (ov < best || (ov == best && oi < besti)) { best = ov; besti = oi; }
            }
            if (col == 0) { redV[w][pxl] = best; redI[w][pxl] = besti; }
        }
    }
    __syncthreads();
    if (t < 64) {
        float bv = redV[0][t]; int bidx = redI[0][t];
#pragma unroll
        for (int q = 1; q < 4; ++q) {
            float v = redV[q][t];
            int   i = redI[q][t];
            if (v < bv || (v == bv && i < bidx)) { bv = v; bidx = i; }
        }
        partV[cT * NPIX + px0 + t] = bv;
        partI[cT * NPIX + px0 + t] = bidx;
    }
}

// ---------------------------------------------------------------------------
// outputs2: fused {final-ids 8-way reduce, emb_st, MSE partials}.
// Per block: one (b, 64-px hw tile) x all 256 channels.
// ---------------------------------------------------------------------------
__global__ __launch_bounds__(256) void k_outputs2(const float* __restrict__ x,
        const float* __restrict__ cb,
        const float* __restrict__ partV, const int* __restrict__ partI,
        float* __restrict__ ids_f, float* __restrict__ out_emb,
        float* __restrict__ partials)
{
    __shared__ int   ids_s[64];
    __shared__ float ev[64][65];                  // [px][c-chunk], +1 pad
    __shared__ float sm[256];

    const int t  = threadIdx.x;
    const int w  = t >> 6, l = t & 63;
    const int bi = blockIdx.x;                    // 512 = 32 b x 16 hw-tiles
    const int b  = bi >> 4;
    const int hw0 = (bi & 15) << 6;
    const int n0 = (b << 10) + hw0;               // pixel base

    if (t < 64) {                                 // final ids (lexicographic)
        const int px = n0 + t;
        float bv = partV[px]; int bix = partI[px];
#pragma unroll
        for (int ct = 1; ct < 8; ++ct) {
            float v = partV[ct * NPIX + px];
            int   i = partI[ct * NPIX + px];
            if (v < bv || (v == bv && i < bix)) { bv = v; bix = i; }
        }
        ids_f[px] = (float)bix;
        ids_s[t] = bix;
    }
    __syncthreads();

    float s = 0.f;
    for (int cc = 0; cc < 4; ++cc) {              // 4 chunks of 64 channels
#pragma unroll
        for (int pp = 0; pp < 16; ++pp) {
            const int px = w * 16 + pp;
            ev[px][l] = cb[(size_t)ids_s[px] * DIM + cc * 64 + l];
        }
        __syncthreads();
#pragma unroll
        for (int ci = 0; ci < 16; ++ci) {
            const int c  = cc * 64 + w * 16 + ci;
            const size_t xi = (((size_t)(b * DIM + c)) << 10) + hw0 + l;
            float xv = x[xi];
            float e  = ev[l][c & 63];             // stride-65 -> conflict-free
            out_emb[xi] = xv + (e - xv);
            float d = xv - e;
            s = fmaf(d, d, s);
        }
        __syncthreads();
    }
    sm[t] = s;
    __syncthreads();
    for (int off = 128; off > 0; off >>= 1) {
        if (t < off) sm[t] += sm[t + off];
        __syncthreads();
    }
    if (t == 0) partials[bi] = sm[0];
}

__global__ __launch_bounds__(256) void k_finalize(const float* __restrict__ partials,
                                                  int nparts,
                                                  float* __restrict__ out_loss)
{
    __shared__ float sm[256];
    const int tid = threadIdx.x;
    float s = 0.f;
    for (int k = tid; k < nparts; k += 256) s += partials[k];
    sm[tid] = s;
    __syncthreads();
    for (int off = 128; off > 0; off >>= 1) {
        if (tid < off) sm[tid] += sm[tid + off];
        __syncthreads();
    }
    if (tid == 0) {
        float m = sm[0] / (float)NELEM;
        out_loss[0] = m + 0.25f * m;
    }
}

// ===========================================================================
// FALLBACK (round-0 passing path, used if ws too small)
// ===========================================================================
__global__ __launch_bounds__(256) void k_enorm(const float* __restrict__ cb,
                                               float* __restrict__ enorm)
{
    const int tid  = threadIdx.x;
    const int lane = tid & 63;
    const int w    = tid >> 6;
    const int k    = blockIdx.x * 4 + w;
    const float* cp = cb + (size_t)k * DIM;
    float s = 0.f;
#pragma unroll
    for (int t = 0; t < 4; ++t) {
        float v = cp[lane + t * 64];
        s = fmaf(v, v, s);
    }
#pragma unroll
    for (int off = 32; off > 0; off >>= 1) s += __shfl_down(s, off);
    if (lane == 0) enorm[k] = s;
}

__global__ __launch_bounds__(256) void k_argmin(const float* __restrict__ x,
                                                const float* __restrict__ cb,
                                                const float* __restrict__ enorm,
                                                float* __restrict__ out_ids)
{
    __shared__ float xs[32][64];
    __shared__ float cbs[32][68];
    __shared__ float nx_l[64];
    __shared__ float nxp[4][64];
    __shared__ float red_v[64][17];
    __shared__ int   red_i[64][17];

    const int tid  = threadIdx.x;
    const int tx   = tid & 15;
    const int ty   = tid >> 4;
    const int pix0 = blockIdx.x * 64;
    const int b    = pix0 >> 10;
    const int hw0  = pix0 & 1023;

    {
        const int p = tid & 63, q = tid >> 6;
        float s = 0.f;
        const float* xp = x + ((size_t)(b * DIM + q * 64) * 1024) + hw0 + p;
        for (int c = 0; c < 64; ++c) {
            float v = xp[c * 1024];
            s = fmaf(v, v, s);
        }
        nxp[q][p] = s;
        __syncthreads();
        if (tid < 64)
            nx_l[tid] = ((nxp[0][tid] + nxp[1][tid]) + nxp[2][tid]) + nxp[3][tid];
        __syncthreads();
    }

    float nx_r[4];
#pragma unroll
    for (int i = 0; i < 4; ++i) nx_r[i] = nx_l[ty * 4 + i];

    float best_v[4];
    int   best_i[4];
#pragma unroll
    for (int i = 0; i < 4; ++i) { best_v[i] = 3.4e38f; best_i[i] = 0; }

    for (int cc = 0; cc < 16; ++cc) {
        float acc[4][4];
#pragma unroll
        for (int i = 0; i < 4; ++i)
#pragma unroll
            for (int j = 0; j < 4; ++j) acc[i][j] = 0.f;

        for (int kcc = 0; kcc < 8; ++kcc) {
            __syncthreads();
            {
                const int p = tid & 63, k0 = tid >> 6;
                const float* xp = x + ((size_t)(b * DIM + kcc * 32) * 1024) + hw0 + p;
#pragma unroll
                for (int tt = 0; tt < 8; ++tt) {
                    int kk = k0 + tt * 4;
                    xs[kk][p] = xp[kk * 1024];
                }
            }
            {
                const int kk = tid & 31, r0 = tid >> 5;
                const float* cp = cb + (size_t)(cc * 64) * DIM + kcc * 32 + kk;
#pragma unroll
                for (int tt = 0; tt < 8; ++tt) {
                    int r = r0 + tt * 8;
                    cbs[kk][r] = cp[r * DIM];
                }
            }
            __syncthreads();
#pragma unroll
            for (int kk = 0; kk < 32; ++kk) {
                float4 A = *(const float4*)&xs[kk][ty * 4];
                float4 B = *(const float4*)&cbs[kk][tx * 4];
                float a[4] = {A.x, A.y, A.z, A.w};
                float bb[4] = {B.x, B.y, B.z, B.w};
#pragma unroll
                for (int i = 0; i < 4; ++i)
#pragma unroll
                    for (int j = 0; j < 4; ++j)
                        acc[i][j] = fmaf(a[i], bb[j], acc[i][j]);
            }
        }

#pragma unroll
        for (int j = 0; j < 4; ++j) {
            const int code = cc * 64 + tx * 4 + j;
            const float nee = enorm[code];
#pragma unroll
            for (int i = 0; i < 4; ++i) {
                float s = (nx_r[i] + nee) - 2.0f * acc[i][j];
                if (s < best_v[i]) { best_v[i] = s; best_i[i] = code; }
            }
        }
    }

#pragma unroll
    for (int i = 0; i < 4; ++i) {
        red_v[ty * 4 + i][tx] = best_v[i];
        red_i[ty * 4 + i][tx] = best_i[i];
    }
    __syncthreads();
    if (tid < 64) {
        float bv = red_v[tid][0];
        int   bi = red_i[tid][0];
#pragma unroll
        for (int tt = 1; tt < 16; ++tt) {
            float v = red_v[tid][tt];
            int   idx = red_i[tid][tt];
            if (v < bv || (v == bv && idx < bi)) { bv = v; bi = idx; }
        }
        out_ids[pix0 + tid] = (float)bi;
    }
}

__global__ __launch_bounds__(256) void k_outputs(const float* __restrict__ x,
                                                 const float* __restrict__ cb,
                                                 const float* __restrict__ ids_f,
                                                 float* __restrict__ out_emb,
                                                 float* __restrict__ partials)
{
    const int tid = threadIdx.x;
    const int gid = blockIdx.x * 256 + tid;      // grid 2048
    float s = 0.f;
#pragma unroll
    for (int it = 0; it < 4; ++it) {
        const int grp = gid + it * 524288;       // float4-group index
        const int e0  = grp << 2;
        const int c   = (e0 >> 10) & 255;
        const int b   = e0 >> 18;
        const int hw  = e0 & 1023;
        const int n0  = (b << 10) + hw;
        float4 idv = *(const float4*)(ids_f + n0);
        float4 xv  = *(const float4*)(x + e0);
        float ev0 = cb[(int)idv.x * DIM + c];
        float ev1 = cb[(int)idv.y * DIM + c];
        float ev2 = cb[(int)idv.z * DIM + c];
        float ev3 = cb[(int)idv.w * DIM + c];
        float4 ov;
        ov.x = xv.x + (ev0 - xv.x);
        ov.y = xv.y + (ev1 - xv.y);
        ov.z = xv.z + (ev2 - xv.z);
        ov.w = xv.w + (ev3 - xv.w);
        *(float4*)(out_emb + e0) = ov;
        float d0 = xv.x - ev0, d1 = xv.y - ev1, d2 = xv.z - ev2, d3 = xv.w - ev3;
        s = fmaf(d0, d0, s); s = fmaf(d1, d1, s);
        s = fmaf(d2, d2, s); s = fmaf(d3, d3, s);
    }
    __shared__ float sm[256];
    sm[tid] = s;
    __syncthreads();
    for (int off = 128; off > 0; off >>= 1) {
        if (tid < off) sm[tid] += sm[tid + off];
        __syncthreads();
    }
    if (tid == 0) partials[blockIdx.x] = sm[0];
}

// ===========================================================================
extern "C" void kernel_launch(void* const* d_in, const int* in_sizes, int n_in,
                              void* d_out, int out_size, void* d_ws, size_t ws_size,
                              hipStream_t stream)
{
    const float* x  = (const float*)d_in[0];   // (32,256,32,32)
    const float* cb = (const float*)d_in[1];   // (1024,256)
    float* out   = (float*)d_out;
    float* ids_f = out;                        // 32768
    float* emb   = out + NPIX;                 // 8388608
    float* loss  = out + NPIX + NELEM;         // 1

    char* wsb = (char*)d_ws;
    const size_t NEED = 36843520ull;
    if (ws_size >= NEED) {
        u16*   Xa = (u16*)(wsb);                     // 16 MB
        u16*   Xb = (u16*)(wsb + 16777216);          // 16 MB
        u16*   Ea = (u16*)(wsb + 33554432);          // 512 KB
        u16*   Eb = (u16*)(wsb + 34078720);          // 512 KB
        float* nx = (float*)(wsb + 34603008);        // 128 KB
        float* ne = (float*)(wsb + 34734080);        // 4 KB
        float* pV = (float*)(wsb + 34738176);        // 1 MB
        int*   pI = (int*)  (wsb + 35786752);        // 1 MB
        float* lp = (float*)(wsb + 36835328);        // 8 KB
        k_prep_x    <<<512,  256, 0, stream>>>(x, Xa, Xb, nx);
        k_prep_e    <<<128,  256, 0, stream>>>(cb, Ea, Eb, ne);
        k_mfma_argmin<<<4096, 256, 0, stream>>>(Xa, Xb, Ea, Eb, nx, ne, pV, pI);
        k_outputs2  <<<512,  256, 0, stream>>>(x, cb, pV, pI, ids_f, emb, lp);
        k_finalize  <<<1,    256, 0, stream>>>(lp, 512, loss);
    } else {
        float* partials = (float*)wsb;         // 2048 floats
        float* enorm    = partials + 2048;     // 1024 floats
        k_enorm   <<<256,  256, 0, stream>>>(cb, enorm);
        k_argmin  <<<512,  256, 0, stream>>>(x, cb, enorm, ids_f);
        k_outputs <<<2048, 256, 0, stream>>>(x, cb, ids_f, emb, partials);
        k_finalize<<<1,    256, 0, stream>>>(partials, 2048, loss);
    }
}